// Round 15
// baseline (743.297 us; speedup 1.0000x reference)
//
#include <hip/hip_runtime.h>
#include <hip/hip_bf16.h>
#include <math.h>

typedef __attribute__((ext_vector_type(4))) float f32x4;
typedef __attribute__((ext_vector_type(8))) __bf16 bf16x8;
typedef __attribute__((ext_vector_type(4))) __bf16 bf16x4;

static constexpr float SCALE = 0.08838834764831845f;     // 128^-0.5
static constexpr float SCALE_LOG2E = 0.1275174482f;      // SCALE * log2(e)

__device__ __forceinline__ void load_lds16(const void* g, void* l) {
  __builtin_amdgcn_global_load_lds(
      (const __attribute__((address_space(1))) void*)g,
      (__attribute__((address_space(3))) void*)l, 16, 0, 0);
}

// ---------------- fp32 -> bf16 cast ----------------
__global__ __launch_bounds__(256) void cast_kernel(const float* __restrict__ s,
                                                   __bf16* __restrict__ d, int n4) {
  int i = blockIdx.x * blockDim.x + threadIdx.x;
  int stride = gridDim.x * blockDim.x;
  for (; i < n4; i += stride) {
    float4 v = reinterpret_cast<const float4*>(s)[i];
    bf16x4 o;
    o[0] = (__bf16)v.x; o[1] = (__bf16)v.y; o[2] = (__bf16)v.z; o[3] = (__bf16)v.w;
    reinterpret_cast<bf16x4*>(d)[i] = o;
  }
}

// ---------------- fused cast of the 6 weight matrices ----------------
__global__ __launch_bounds__(256) void cast_weights(
    const float* __restrict__ wq, const float* __restrict__ wk,
    const float* __restrict__ wv, const float* __restrict__ wo,
    const float* __restrict__ w1, const float* __restrict__ w2,
    __bf16* __restrict__ dq, __bf16* __restrict__ dk,
    __bf16* __restrict__ dv, __bf16* __restrict__ dwo,
    __bf16* __restrict__ d1, __bf16* __restrict__ d2) {
  int i = blockIdx.x * blockDim.x + threadIdx.x;
  int stride = gridDim.x * blockDim.x;
  for (; i < 3145728; i += stride) {
    const float* s; __bf16* d; int j;
    if (i < 262144)       { s = wq; d = dq;  j = i; }
    else if (i < 524288)  { s = wk; d = dk;  j = i - 262144; }
    else if (i < 786432)  { s = wv; d = dv;  j = i - 524288; }
    else if (i < 1048576) { s = wo; d = dwo; j = i - 786432; }
    else if (i < 2097152) { s = w1; d = d1;  j = i - 1048576; }
    else                  { s = w2; d = d2;  j = i - 2097152; }
    float4 v = reinterpret_cast<const float4*>(s)[j];
    bf16x4 o;
    o[0] = (__bf16)v.x; o[1] = (__bf16)v.y; o[2] = (__bf16)v.z; o[3] = (__bf16)v.w;
    reinterpret_cast<bf16x4*>(d)[j] = o;
  }
}

// ---------------- fp32 -> bf16 cast with scale (for attn bias) ----------------
__global__ __launch_bounds__(256) void scale_cast_kernel(const float* __restrict__ s,
                                                         __bf16* __restrict__ d, int n4) {
  int i = blockIdx.x * blockDim.x + threadIdx.x;
  int stride = gridDim.x * blockDim.x;
  for (; i < n4; i += stride) {
    float4 v = reinterpret_cast<const float4*>(s)[i];
    bf16x4 o;
    o[0] = (__bf16)(v.x * SCALE_LOG2E); o[1] = (__bf16)(v.y * SCALE_LOG2E);
    o[2] = (__bf16)(v.z * SCALE_LOG2E); o[3] = (__bf16)(v.w * SCALE_LOG2E);
    reinterpret_cast<bf16x4*>(d)[i] = o;
  }
}

// ======== 256x256 8-wave bf16 GEMM, dbuf + full-tile-cover drain (r8, proven) ====
// EPI: 0 = bf16, 1 = bf16 relu, 2 = f32, 3 = bf16 transposed-per-group (VT)
template <int EPI>
__global__ __launch_bounds__(512, 2) void gemm_bt(
    const __bf16* __restrict__ A, const __bf16* __restrict__ Bw,
    const float* __restrict__ bvec, __bf16* __restrict__ Cb,
    float* __restrict__ Cf, int M, int N, int K) {
  __shared__ __align__(16) char sm[131072];

  const int ntn = N >> 8;
  const int nwg = gridDim.x;
  const int bid = blockIdx.x;
  const int b = (bid & 7) * (nwg >> 3) + (bid >> 3);
  const int tm = b / ntn, tn = b % ntn;
  const int t = threadIdx.x, lane = t & 63;
  const int w = t >> 6;
  const int wm = w >> 2, wn = w & 3;
  const int l15 = lane & 15, lq = lane >> 4;

  f32x4 acc[8][4] = {};

  const int r0 = t >> 3;
  const int r1 = r0 + 64;
  const int kb0 = (((t & 7) << 4) ^ ((r0 & 7) << 4));
  const int wbase = w << 10;

  auto stage = [&](int kt, int p) {
    char* base = sm + (p << 16);
    const size_t kofs = (size_t)(kb0 >> 1) + ((size_t)kt << 6);
#pragma unroll
    for (int h = 0; h < 2; ++h) {
      const __bf16* gA = A + (size_t)((tm << 8) + (h << 7) + r0) * K + kofs;
      const __bf16* gA2 = A + (size_t)((tm << 8) + (h << 7) + r1) * K + kofs;
      char* lA = base + (h << 14) + wbase;
      load_lds16(gA, lA);
      load_lds16(gA2, lA + 8192);
      const __bf16* gB = Bw + (size_t)((tn << 8) + (h << 7) + r0) * K + kofs;
      const __bf16* gB2 = Bw + (size_t)((tn << 8) + (h << 7) + r1) * K + kofs;
      char* lB = base + 32768 + (h << 14) + wbase;
      load_lds16(gB, lB);
      load_lds16(gB2, lB + 8192);
    }
  };

  stage(0, 0);
  __syncthreads();

  const int NT = K >> 6;
  const int rbB = (wn & 1) << 6;
  for (int kt = 0; kt < NT; ++kt) {
    const int p = kt & 1;
    const char* Ab = sm + (p << 16) + (wm << 14);
    const char* Bb = sm + (p << 16) + 32768 + ((wn >> 1) << 14);
    if (kt + 1 < NT) stage(kt + 1, p ^ 1);

    bf16x8 bfv[4][2];
#pragma unroll
    for (int nf = 0; nf < 4; ++nf) {
      const int r = rbB + (nf << 4) + l15;
      const int sw = (r & 7) << 4;
#pragma unroll
      for (int ks = 0; ks < 2; ++ks) {
        const int lb = (ks << 6) + (lq << 4);
        bfv[nf][ks] = *(const bf16x8*)(Bb + r * 128 + (lb ^ sw));
      }
    }
#pragma unroll
    for (int q = 0; q < 4; ++q) {
      bf16x8 af[2][2];
#pragma unroll
      for (int dm = 0; dm < 2; ++dm) {
        const int r = (((q << 1) + dm) << 4) + l15;
        const int sw = (r & 7) << 4;
#pragma unroll
        for (int ks = 0; ks < 2; ++ks) {
          const int lb = (ks << 6) + (lq << 4);
          af[dm][ks] = *(const bf16x8*)(Ab + r * 128 + (lb ^ sw));
        }
      }
#pragma unroll
      for (int ks = 0; ks < 2; ++ks)
#pragma unroll
        for (int dm = 0; dm < 2; ++dm)
#pragma unroll
          for (int nf = 0; nf < 4; ++nf)
            acc[(q << 1) + dm][nf] = __builtin_amdgcn_mfma_f32_16x16x32_bf16(
                af[dm][ks], bfv[nf][ks], acc[(q << 1) + dm][nf], 0, 0, 0);
    }
    __syncthreads();
  }

  const int row0 = (tm << 8) + (wm << 7) + (lq << 2);
  const int col0 = (tn << 8) + (wn << 6) + l15;
#pragma unroll
  for (int nf = 0; nf < 4; ++nf) {
    const int col = col0 + (nf << 4);
    const float bv = bvec[col];
#pragma unroll
    for (int mf = 0; mf < 8; ++mf) {
#pragma unroll
      for (int r = 0; r < 4; ++r) {
        const int row = row0 + (mf << 4) + r;
        float v = acc[mf][nf][r] + bv;
        if (EPI == 1) v = fmaxf(v, 0.f);
        if (EPI == 2) {
          Cf[(size_t)row * N + col] = v;
        } else if (EPI == 3) {
          size_t vt = ((size_t)(row >> 7) << 17) + ((size_t)(col & 127) << 10) +
                      ((row & 127) << 3) + (col >> 7);
          Cb[vt] = (__bf16)v;
        } else {
          Cb[(size_t)row * N + col] = (__bf16)v;
        }
      }
    }
  }
}

// ======== 256x256 8-wave PHASED GEMM (m201-style 4-phase/K-tile overlap) ========
// Same LDS geometry/staging/swizzle as gemm_bt. Per K-tile:
//  pre: 8 B-reads (hoisted, reused all phases) — B in regs across the tile
//  phase q=0..3: [4 A-reads (+q0: stage-issue)] ; s_barrier ; lgkmcnt(0) ;
//                sched_barrier ; setprio(1) 16 MFMA setprio(0) ;
//                (q3: vmcnt(0)) ; s_barrier
// ds_reads fly during the barrier wait and overlap other waves' MFMA drain.
// LDS traffic budget = 24 reads/wave/tile (same as gemm_bt; r4's 3x-B mistake fixed).
template <int EPI>
__global__ __launch_bounds__(512, 2) void gemm_ph(
    const __bf16* __restrict__ A, const __bf16* __restrict__ Bw,
    const float* __restrict__ bvec, __bf16* __restrict__ Cb,
    float* __restrict__ Cf, int M, int N, int K) {
  __shared__ __align__(16) char sm[131072];

  const int ntn = N >> 8;
  const int nwg = gridDim.x;
  const int bid = blockIdx.x;
  const int b = (bid & 7) * (nwg >> 3) + (bid >> 3);
  const int tm = b / ntn, tn = b % ntn;
  const int t = threadIdx.x, lane = t & 63;
  const int w = t >> 6;
  const int wm = w >> 2, wn = w & 3;
  const int l15 = lane & 15, lq = lane >> 4;

  f32x4 acc[8][4] = {};

  const int r0 = t >> 3;
  const int r1 = r0 + 64;
  const int kb0 = (((t & 7) << 4) ^ ((r0 & 7) << 4));
  const int wbase = w << 10;

  auto stage = [&](int kt, int p) {
    char* base = sm + (p << 16);
    const size_t kofs = (size_t)(kb0 >> 1) + ((size_t)kt << 6);
#pragma unroll
    for (int h = 0; h < 2; ++h) {
      const __bf16* gA = A + (size_t)((tm << 8) + (h << 7) + r0) * K + kofs;
      const __bf16* gA2 = A + (size_t)((tm << 8) + (h << 7) + r1) * K + kofs;
      char* lA = base + (h << 14) + wbase;
      load_lds16(gA, lA);
      load_lds16(gA2, lA + 8192);
      const __bf16* gB = Bw + (size_t)((tn << 8) + (h << 7) + r0) * K + kofs;
      const __bf16* gB2 = Bw + (size_t)((tn << 8) + (h << 7) + r1) * K + kofs;
      char* lB = base + 32768 + (h << 14) + wbase;
      load_lds16(gB, lB);
      load_lds16(gB2, lB + 8192);
    }
  };

  stage(0, 0);
  asm volatile("s_waitcnt vmcnt(0)\ns_barrier" ::: "memory");

  const int NT = K >> 6;
  const int rbB = (wn & 1) << 6;
  for (int kt = 0; kt < NT; ++kt) {
    const int p = kt & 1;
    const char* Ab = sm + (p << 16) + (wm << 14);
    const char* Bb = sm + (p << 16) + 32768 + ((wn >> 1) << 14);

    // B-frags hoisted once per tile (kept in regs across phases)
    bf16x8 bfv[4][2];
#pragma unroll
    for (int nf = 0; nf < 4; ++nf) {
      const int r = rbB + (nf << 4) + l15;
      const int sw = (r & 7) << 4;
#pragma unroll
      for (int ks = 0; ks < 2; ++ks) {
        const int lb = (ks << 6) + (lq << 4);
        bfv[nf][ks] = *(const bf16x8*)(Bb + r * 128 + (lb ^ sw));
      }
    }

#pragma unroll
    for (int q = 0; q < 4; ++q) {
      bf16x8 af[2][2];
#pragma unroll
      for (int dm = 0; dm < 2; ++dm) {
        const int r = (((q << 1) + dm) << 4) + l15;
        const int sw = (r & 7) << 4;
#pragma unroll
        for (int ks = 0; ks < 2; ++ks) {
          const int lb = (ks << 6) + (lq << 4);
          af[dm][ks] = *(const bf16x8*)(Ab + r * 128 + (lb ^ sw));
        }
      }
      if (q == 0 && kt + 1 < NT) stage(kt + 1, p ^ 1);
      asm volatile("s_barrier" ::: "memory");
      asm volatile("s_waitcnt lgkmcnt(0)" ::: "memory");
      __builtin_amdgcn_sched_barrier(0);
      __builtin_amdgcn_s_setprio(1);
#pragma unroll
      for (int ks = 0; ks < 2; ++ks)
#pragma unroll
        for (int dm = 0; dm < 2; ++dm)
#pragma unroll
          for (int nf = 0; nf < 4; ++nf)
            acc[(q << 1) + dm][nf] = __builtin_amdgcn_mfma_f32_16x16x32_bf16(
                af[dm][ks], bfv[nf][ks], acc[(q << 1) + dm][nf], 0, 0, 0);
      __builtin_amdgcn_s_setprio(0);
      if (q == 3) asm volatile("s_waitcnt vmcnt(0)" ::: "memory");
      asm volatile("s_barrier" ::: "memory");
    }
  }

  const int row0 = (tm << 8) + (wm << 7) + (lq << 2);
  const int col0 = (tn << 8) + (wn << 6) + l15;
#pragma unroll
  for (int nf = 0; nf < 4; ++nf) {
    const int col = col0 + (nf << 4);
    const float bv = bvec[col];
#pragma unroll
    for (int mf = 0; mf < 8; ++mf) {
#pragma unroll
      for (int r = 0; r < 4; ++r) {
        const int row = row0 + (mf << 4) + r;
        float v = acc[mf][nf][r] + bv;
        if (EPI == 1) v = fmaxf(v, 0.f);
        if (EPI == 2)
          Cf[(size_t)row * N + col] = v;
        else
          Cb[(size_t)row * N + col] = (__bf16)v;
      }
    }
  }
}

// ---------------- flash attention, QBLK=128 (8 waves), no-max exp2 softmax (r14) ---
__global__ __launch_bounds__(512, 2) void attn_flash(
    const __bf16* __restrict__ Q, const __bf16* __restrict__ K,
    const __bf16* __restrict__ VT, const __bf16* __restrict__ biasS,
    __bf16* __restrict__ ctx) {
  __shared__ __bf16 Ks[64 * 128];
  __shared__ __bf16 VTs[128 * 64];
  __shared__ __bf16 Ps[8][16 * 64];

  const int bid = blockIdx.x;
  const int b = ((bid & 7) << 7) | (bid >> 3);
  const int g = b >> 3;
  const int q0 = (b & 7) << 7;
  const size_t goff = (size_t)g << 17;
  const __bf16* Qg = Q + goff;
  const __bf16* Kg = K + goff;
  const __bf16* VTg = VT + goff;

  const int t = threadIdx.x, w = t >> 6, lane = t & 63;
  const int l15 = lane & 15, lq = lane >> 4;
  const int qg = q0 + (w << 4) + l15;

  bf16x8 qf[4];
  {
    const __bf16* qrow = Qg + (size_t)qg * 128 + (lq << 3);
#pragma unroll
    for (int ec = 0; ec < 4; ++ec) qf[ec] = *(const bf16x8*)(qrow + (ec << 5));
  }
  const __bf16* bSr = biasS + ((size_t)qg << 10) + (lq << 2);

  float lrun = 0.f;
  f32x4 cacc[8] = {};

  for (int kb = 0; kb < 1024; kb += 64) {
    {
      int srow = lane >> 4;
      int sbo = (lane & 15) << 4;
#pragma unroll
      for (int i = 0; i < 2; ++i) {
        int c = (w << 1) + i;
        int r = (c << 2) + srow;
        int ke = (sbo ^ ((r & 7) << 4)) >> 1;
        load_lds16(Kg + (size_t)(kb + r) * 128 + ke, (char*)Ks + (c << 10));
      }
    }
    {
      int srow = lane >> 3;
      int sbo = (lane & 7) << 4;
#pragma unroll
      for (int i = 0; i < 2; ++i) {
        int c = (w << 1) + i;
        int e = (c << 3) + srow;
        int ke = kb + ((sbo ^ ((e & 7) << 4)) >> 1);
        load_lds16(VTg + (size_t)e * 1024 + ke, (char*)VTs + (c << 10));
      }
    }
    __syncthreads();

    f32x4 sacc[4] = {};
    __builtin_amdgcn_s_setprio(1);
#pragma unroll
    for (int ec = 0; ec < 4; ++ec) {
      const int lb = (ec << 6) + (lq << 4);
#pragma unroll
      for (int kn = 0; kn < 4; ++kn) {
        int rb = (kn << 4) + l15;
        bf16x8 kf = *(const bf16x8*)((const char*)Ks + rb * 256 + (lb ^ ((rb & 7) << 4)));
        sacc[kn] = __builtin_amdgcn_mfma_f32_16x16x32_bf16(kf, qf[ec], sacc[kn], 0, 0, 0);
      }
    }
    __builtin_amdgcn_s_setprio(0);

    const __bf16* bt = bSr + kb;
#pragma unroll
    for (int kn = 0; kn < 4; ++kn) {
      bf16x4 bb = *(const bf16x4*)(bt + (kn << 4));
      bf16x4 pk;
#pragma unroll
      for (int r = 0; r < 4; ++r) {
        float p = exp2f(fmaf(sacc[kn][r], SCALE_LOG2E, (float)bb[r]));
        lrun += p;
        pk[r] = (__bf16)p;
      }
      int bo = (kn << 5) + (lq << 3);
      *(bf16x4*)((char*)Ps[w] + l15 * 128 + (bo ^ ((l15 & 7) << 4))) = pk;
    }
    asm volatile("s_waitcnt lgkmcnt(0)" ::: "memory");
    __builtin_amdgcn_sched_barrier(0);

    __builtin_amdgcn_s_setprio(1);
#pragma unroll
    for (int ks = 0; ks < 2; ++ks) {
      const int lb = (ks << 6) + (lq << 4);
      bf16x8 paf = *(const bf16x8*)((const char*)Ps[w] + l15 * 128 + (lb ^ ((l15 & 7) << 4)));
#pragma unroll
      for (int et = 0; et < 8; ++et) {
        int e = (et << 4) + l15;
        bf16x8 vf = *(const bf16x8*)((const char*)VTs + e * 128 + (lb ^ ((e & 7) << 4)));
        cacc[et] = __builtin_amdgcn_mfma_f32_16x16x32_bf16(paf, vf, cacc[et], 0, 0, 0);
      }
    }
    __builtin_amdgcn_s_setprio(0);
    __syncthreads();
  }

  lrun += __shfl_xor(lrun, 16);
  lrun += __shfl_xor(lrun, 32);
  float lrunR[4];
#pragma unroll
  for (int r = 0; r < 4; ++r)
    lrunR[r] = __shfl(lrun, (lane & 48) + ((lane & 48) >> 2) + r);
  __bf16* cg = ctx + goff;
  const int qr = q0 + (w << 4) + (lq << 2);
#pragma unroll
  for (int et = 0; et < 8; ++et)
#pragma unroll
    for (int r = 0; r < 4; ++r) {
      float v = cacc[et][r] / lrunR[r];
      cg[(size_t)(qr + r) * 128 + (et << 4) + l15] = (__bf16)v;
    }
}

// ---------------- attn[0] full softmax matrix (group 0) ----------------
__global__ __launch_bounds__(256) void attn_head0(
    const __bf16* __restrict__ Q, const __bf16* __restrict__ K,
    const float* __restrict__ bias, float* __restrict__ out) {
  __shared__ float qrow[128];
  __shared__ float red[8];
  const int q = blockIdx.x, t = threadIdx.x;
  if (t < 128) qrow[t] = (float)Q[(size_t)q * 128 + t];
  __syncthreads();
  float s[4];
#pragma unroll
  for (int c = 0; c < 4; ++c) {
    int kc = (c << 8) + t;
    const __bf16* kr = K + (size_t)kc * 128;
    float dot = 0.f;
#pragma unroll
    for (int e = 0; e < 128; e += 8) {
      bf16x8 kv = *(const bf16x8*)(kr + e);
#pragma unroll
      for (int j = 0; j < 8; ++j) dot += qrow[e + j] * (float)kv[j];
    }
    s[c] = (dot + bias[(size_t)q * 1024 + kc]) * SCALE;
  }
  float mx = fmaxf(fmaxf(s[0], s[1]), fmaxf(s[2], s[3]));
#pragma unroll
  for (int d = 32; d >= 1; d >>= 1) mx = fmaxf(mx, __shfl_xor(mx, d));
  const int w = t >> 6, lane = t & 63;
  if (lane == 0) red[w] = mx;
  __syncthreads();
  mx = fmaxf(fmaxf(red[0], red[1]), fmaxf(red[2], red[3]));
  float ex[4], sum = 0.f;
#pragma unroll
  for (int c = 0; c < 4; ++c) { ex[c] = __expf(s[c] - mx); sum += ex[c]; }
#pragma unroll
  for (int d = 32; d >= 1; d >>= 1) sum += __shfl_xor(sum, d);
  __syncthreads();
  if (lane == 0) red[4 + w] = sum;
  __syncthreads();
  sum = red[4] + red[5] + red[6] + red[7];
  float inv = 1.f / sum;
#pragma unroll
  for (int c = 0; c < 4; ++c) out[(size_t)q * 1024 + (c << 8) + t] = ex[c] * inv;
}

// ---------------- LayerNorm(a + b) * g + beta ----------------
template <int A_BF16, int B_BF16>
__global__ __launch_bounds__(256) void ln_res(
    const void* __restrict__ aptr, const void* __restrict__ bptr,
    const float* __restrict__ gam, const float* __restrict__ bet,
    float* __restrict__ outf, __bf16* __restrict__ outb) {
  __shared__ float red[8];
  const int row = blockIdx.x, t = threadIdx.x;
  const size_t base = (size_t)row << 10;
  float a0, a1, a2, a3;
  if (A_BF16) {
    bf16x4 va = reinterpret_cast<const bf16x4*>((const __bf16*)aptr + base)[t];
    a0 = (float)va[0]; a1 = (float)va[1]; a2 = (float)va[2]; a3 = (float)va[3];
  } else {
    float4 va = reinterpret_cast<const float4*>((const float*)aptr + base)[t];
    a0 = va.x; a1 = va.y; a2 = va.z; a3 = va.w;
  }
  float b0, b1, b2, b3;
  if (B_BF16) {
    bf16x4 vb = reinterpret_cast<const bf16x4*>((const __bf16*)bptr + base)[t];
    b0 = (float)vb[0]; b1 = (float)vb[1]; b2 = (float)vb[2]; b3 = (float)vb[3];
  } else {
    float4 vb = reinterpret_cast<const float4*>((const float*)bptr + base)[t];
    b0 = vb.x; b1 = vb.y; b2 = vb.z; b3 = vb.w;
  }
  float v0 = a0 + b0, v1 = a1 + b1, v2 = a2 + b2, v3 = a3 + b3;
  float s = v0 + v1 + v2 + v3;
  float qq = v0 * v0 + v1 * v1 + v2 * v2 + v3 * v3;
#pragma unroll
  for (int d = 32; d >= 1; d >>= 1) {
    s += __shfl_xor(s, d);
    qq += __shfl_xor(qq, d);
  }
  const int w = t >> 6, lane = t & 63;
  if (lane == 0) { red[w] = s; red[4 + w] = qq; }
  __syncthreads();
  s = red[0] + red[1] + red[2] + red[3];
  qq = red[4] + red[5] + red[6] + red[7];
  const float mu = s * (1.f / 1024.f);
  const float var = qq * (1.f / 1024.f) - mu * mu;
  const float rs = rsqrtf(var + 1e-5f);
  float4 g4 = reinterpret_cast<const float4*>(gam)[t];
  float4 b4 = reinterpret_cast<const float4*>(bet)[t];
  float o0 = (v0 - mu) * rs * g4.x + b4.x;
  float o1 = (v1 - mu) * rs * g4.y + b4.y;
  float o2 = (v2 - mu) * rs * g4.z + b4.z;
  float o3 = (v3 - mu) * rs * g4.w + b4.w;
  if (outf) reinterpret_cast<float4*>(outf + base)[t] = make_float4(o0, o1, o2, o3);
  if (outb) {
    bf16x4 ob;
    ob[0] = (__bf16)o0; ob[1] = (__bf16)o1; ob[2] = (__bf16)o2; ob[3] = (__bf16)o3;
    reinterpret_cast<bf16x4*>(outb + base)[t] = ob;
  }
}

extern "C" void kernel_launch(void* const* d_in, const int* in_sizes, int n_in,
                              void* d_out, int out_size, void* d_ws, size_t ws_size,
                              hipStream_t stream) {
  (void)in_sizes; (void)n_in; (void)out_size; (void)ws_size;
  const float* x    = (const float*)d_in[0];
  const float* bias = (const float*)d_in[1];
  const float* Wq   = (const float*)d_in[2];
  const float* bq   = (const float*)d_in[3];
  const float* Wk   = (const float*)d_in[4];
  const float* bk   = (const float*)d_in[5];
  const float* Wv   = (const float*)d_in[6];
  const float* bv   = (const float*)d_in[7];
  const float* Wo   = (const float*)d_in[8];
  const float* bo   = (const float*)d_in[9];
  const float* g1   = (const float*)d_in[10];
  const float* b1l  = (const float*)d_in[11];
  const float* W1   = (const float*)d_in[12];
  const float* b1f  = (const float*)d_in[13];
  const float* W2   = (const float*)d_in[14];
  const float* b2f  = (const float*)d_in[15];
  const float* g2   = (const float*)d_in[16];
  const float* b2l  = (const float*)d_in[17];

  // ---- workspace layout (~186 MB) ----
  char* ws = (char*)d_ws;
  size_t off = 0;
  auto alloc = [&](size_t bytes) {
    char* p = ws + off;
    off += (bytes + 255) & ~(size_t)255;
    return p;
  };
  __bf16* wqb  = (__bf16*)alloc(2097152);
  __bf16* wkb  = (__bf16*)alloc(2097152);
  __bf16* wvb  = (__bf16*)alloc(2097152);
  __bf16* wob  = (__bf16*)alloc(2097152);
  __bf16* w1b  = (__bf16*)alloc(8388608);
  __bf16* w2b  = (__bf16*)alloc(8388608);
  __bf16* biasS = (__bf16*)alloc(2097152);
  __bf16* xb   = (__bf16*)alloc(33554432);
  __bf16* Qb   = (__bf16*)alloc(4ull * 33554432);
  __bf16* Kb   = Qb + 16777216;
  __bf16* VTb  = Kb + 16777216;
  __bf16* ctxb = VTb + 16777216;
  __bf16* hb   = Qb;
  __bf16* res1b = xb;
  __bf16* attn_out_b = Qb;

  float* out2     = (float*)d_out;
  float* selfattn = (float*)d_out + 16777216;
  float* ff       = out2;

  // casts
  cast_kernel<<<2048, 256, 0, stream>>>(x, xb, 16777216 / 4);
  cast_weights<<<2048, 256, 0, stream>>>(Wq, Wk, Wv, Wo, W1, W2,
                                         wqb, wkb, wvb, wob, w1b, w2b);
  scale_cast_kernel<<<512, 256, 0, stream>>>(bias, biasS, 1048576 / 4);

  // QKV projections (r8 template — control group)
  gemm_bt<0><<<64 * 4, 512, 0, stream>>>(xb, wqb, bq, Qb, nullptr, 16384, 1024, 1024);
  gemm_bt<0><<<64 * 4, 512, 0, stream>>>(xb, wkb, bk, Kb, nullptr, 16384, 1024, 1024);
  gemm_bt<3><<<64 * 4, 512, 0, stream>>>(xb, wvb, bv, VTb, nullptr, 16384, 1024, 1024);

  // attention (QBLK=128)
  attn_head0<<<1024, 256, 0, stream>>>(Qb, Kb, bias, selfattn);
  attn_flash<<<128 * 8, 512, 0, stream>>>(Qb, Kb, VTb, biasS, ctxb);

  // output projection (r8 template — control group)
  gemm_bt<0><<<64 * 4, 512, 0, stream>>>(ctxb, wob, bo, attn_out_b, nullptr, 16384, 1024, 1024);

  // ln1(attn_out + x[bf16]) -> res1 bf16
  ln_res<1, 1><<<16384, 256, 0, stream>>>(attn_out_b, xb, g1, b1l, nullptr, res1b);

  // FFN (phased template — experiment group)
  gemm_ph<1><<<64 * 16, 512, 0, stream>>>(res1b, w1b, b1f, hb, nullptr, 16384, 4096, 1024);
  gemm_ph<2><<<64 * 4, 512, 0, stream>>>(hb, w2b, b2f, nullptr, ff, 16384, 1024, 4096);

  // ln2(ff + res1) -> out2
  ln_res<0, 1><<<16384, 256, 0, stream>>>(ff, res1b, g2, b2l, out2, nullptr);
}

// Round 16
// 668.328 us; speedup vs baseline: 1.1122x; 1.1122x over previous
//
#include <hip/hip_runtime.h>
#include <hip/hip_bf16.h>
#include <math.h>

typedef __attribute__((ext_vector_type(4))) float f32x4;
typedef __attribute__((ext_vector_type(8))) __bf16 bf16x8;
typedef __attribute__((ext_vector_type(4))) __bf16 bf16x4;

static constexpr float SCALE = 0.08838834764831845f;     // 128^-0.5
static constexpr float SCALE_LOG2E = 0.1275174482f;      // SCALE * log2(e)

__device__ __forceinline__ void load_lds16(const void* g, void* l) {
  __builtin_amdgcn_global_load_lds(
      (const __attribute__((address_space(1))) void*)g,
      (__attribute__((address_space(3))) void*)l, 16, 0, 0);
}

// ---------------- fp32 -> bf16 cast ----------------
__global__ __launch_bounds__(256) void cast_kernel(const float* __restrict__ s,
                                                   __bf16* __restrict__ d, int n4) {
  int i = blockIdx.x * blockDim.x + threadIdx.x;
  int stride = gridDim.x * blockDim.x;
  for (; i < n4; i += stride) {
    float4 v = reinterpret_cast<const float4*>(s)[i];
    bf16x4 o;
    o[0] = (__bf16)v.x; o[1] = (__bf16)v.y; o[2] = (__bf16)v.z; o[3] = (__bf16)v.w;
    reinterpret_cast<bf16x4*>(d)[i] = o;
  }
}

// ---------------- fused cast of the 6 weight matrices ----------------
__global__ __launch_bounds__(256) void cast_weights(
    const float* __restrict__ wq, const float* __restrict__ wk,
    const float* __restrict__ wv, const float* __restrict__ wo,
    const float* __restrict__ w1, const float* __restrict__ w2,
    __bf16* __restrict__ dq, __bf16* __restrict__ dk,
    __bf16* __restrict__ dv, __bf16* __restrict__ dwo,
    __bf16* __restrict__ d1, __bf16* __restrict__ d2) {
  int i = blockIdx.x * blockDim.x + threadIdx.x;
  int stride = gridDim.x * blockDim.x;
  for (; i < 3145728; i += stride) {
    const float* s; __bf16* d; int j;
    if (i < 262144)       { s = wq; d = dq;  j = i; }
    else if (i < 524288)  { s = wk; d = dk;  j = i - 262144; }
    else if (i < 786432)  { s = wv; d = dv;  j = i - 524288; }
    else if (i < 1048576) { s = wo; d = dwo; j = i - 786432; }
    else if (i < 2097152) { s = w1; d = d1;  j = i - 1048576; }
    else                  { s = w2; d = d2;  j = i - 2097152; }
    float4 v = reinterpret_cast<const float4*>(s)[j];
    bf16x4 o;
    o[0] = (__bf16)v.x; o[1] = (__bf16)v.y; o[2] = (__bf16)v.z; o[3] = (__bf16)v.w;
    reinterpret_cast<bf16x4*>(d)[j] = o;
  }
}

// ---------------- fp32 -> bf16 cast with scale (for attn bias) ----------------
__global__ __launch_bounds__(256) void scale_cast_kernel(const float* __restrict__ s,
                                                         __bf16* __restrict__ d, int n4) {
  int i = blockIdx.x * blockDim.x + threadIdx.x;
  int stride = gridDim.x * blockDim.x;
  for (; i < n4; i += stride) {
    float4 v = reinterpret_cast<const float4*>(s)[i];
    bf16x4 o;
    o[0] = (__bf16)(v.x * SCALE_LOG2E); o[1] = (__bf16)(v.y * SCALE_LOG2E);
    o[2] = (__bf16)(v.z * SCALE_LOG2E); o[3] = (__bf16)(v.w * SCALE_LOG2E);
    reinterpret_cast<bf16x4*>(d)[i] = o;
  }
}

// ---------------- selfattn normalize: out[q][k] = Pun[q][k] * inv0[q] ----------------
__global__ __launch_bounds__(256) void norm_p(const __bf16* __restrict__ Pun,
                                              const float* __restrict__ inv0,
                                              float* __restrict__ out) {
  const int q = blockIdx.x, t = threadIdx.x;
  const float iv = inv0[q];
  bf16x4 p = reinterpret_cast<const bf16x4*>(Pun + ((size_t)q << 10))[t];
  float4 o = make_float4((float)p[0] * iv, (float)p[1] * iv,
                         (float)p[2] * iv, (float)p[3] * iv);
  reinterpret_cast<float4*>(out + ((size_t)q << 10))[t] = o;
}

// ======== 256x256 8-wave bf16 GEMM, dbuf + full-tile-cover drain (r8, proven) ====
// EPI: 0 = bf16, 1 = bf16 relu, 2 = f32, 3 = bf16 transposed-per-group (VT)
template <int EPI>
__global__ __launch_bounds__(512, 2) void gemm_bt(
    const __bf16* __restrict__ A, const __bf16* __restrict__ Bw,
    const float* __restrict__ bvec, __bf16* __restrict__ Cb,
    float* __restrict__ Cf, int M, int N, int K) {
  __shared__ __align__(16) char sm[131072];

  const int ntn = N >> 8;
  const int nwg = gridDim.x;
  const int bid = blockIdx.x;
  const int b = (bid & 7) * (nwg >> 3) + (bid >> 3);
  const int tm = b / ntn, tn = b % ntn;
  const int t = threadIdx.x, lane = t & 63;
  const int w = t >> 6;
  const int wm = w >> 2, wn = w & 3;
  const int l15 = lane & 15, lq = lane >> 4;

  f32x4 acc[8][4] = {};

  const int r0 = t >> 3;
  const int r1 = r0 + 64;
  const int kb0 = (((t & 7) << 4) ^ ((r0 & 7) << 4));
  const int wbase = w << 10;

  auto stage = [&](int kt, int p) {
    char* base = sm + (p << 16);
    const size_t kofs = (size_t)(kb0 >> 1) + ((size_t)kt << 6);
#pragma unroll
    for (int h = 0; h < 2; ++h) {
      const __bf16* gA = A + (size_t)((tm << 8) + (h << 7) + r0) * K + kofs;
      const __bf16* gA2 = A + (size_t)((tm << 8) + (h << 7) + r1) * K + kofs;
      char* lA = base + (h << 14) + wbase;
      load_lds16(gA, lA);
      load_lds16(gA2, lA + 8192);
      const __bf16* gB = Bw + (size_t)((tn << 8) + (h << 7) + r0) * K + kofs;
      const __bf16* gB2 = Bw + (size_t)((tn << 8) + (h << 7) + r1) * K + kofs;
      char* lB = base + 32768 + (h << 14) + wbase;
      load_lds16(gB, lB);
      load_lds16(gB2, lB + 8192);
    }
  };

  stage(0, 0);
  __syncthreads();

  const int NT = K >> 6;
  const int rbB = (wn & 1) << 6;
  for (int kt = 0; kt < NT; ++kt) {
    const int p = kt & 1;
    const char* Ab = sm + (p << 16) + (wm << 14);
    const char* Bb = sm + (p << 16) + 32768 + ((wn >> 1) << 14);
    if (kt + 1 < NT) stage(kt + 1, p ^ 1);

    bf16x8 bfv[4][2];
#pragma unroll
    for (int nf = 0; nf < 4; ++nf) {
      const int r = rbB + (nf << 4) + l15;
      const int sw = (r & 7) << 4;
#pragma unroll
      for (int ks = 0; ks < 2; ++ks) {
        const int lb = (ks << 6) + (lq << 4);
        bfv[nf][ks] = *(const bf16x8*)(Bb + r * 128 + (lb ^ sw));
      }
    }
#pragma unroll
    for (int q = 0; q < 4; ++q) {
      bf16x8 af[2][2];
#pragma unroll
      for (int dm = 0; dm < 2; ++dm) {
        const int r = (((q << 1) + dm) << 4) + l15;
        const int sw = (r & 7) << 4;
#pragma unroll
        for (int ks = 0; ks < 2; ++ks) {
          const int lb = (ks << 6) + (lq << 4);
          af[dm][ks] = *(const bf16x8*)(Ab + r * 128 + (lb ^ sw));
        }
      }
#pragma unroll
      for (int ks = 0; ks < 2; ++ks)
#pragma unroll
        for (int dm = 0; dm < 2; ++dm)
#pragma unroll
          for (int nf = 0; nf < 4; ++nf)
            acc[(q << 1) + dm][nf] = __builtin_amdgcn_mfma_f32_16x16x32_bf16(
                af[dm][ks], bfv[nf][ks], acc[(q << 1) + dm][nf], 0, 0, 0);
    }
    __syncthreads();
  }

  const int row0 = (tm << 8) + (wm << 7) + (lq << 2);
  const int col0 = (tn << 8) + (wn << 6) + l15;
#pragma unroll
  for (int nf = 0; nf < 4; ++nf) {
    const int col = col0 + (nf << 4);
    const float bv = bvec[col];
#pragma unroll
    for (int mf = 0; mf < 8; ++mf) {
#pragma unroll
      for (int r = 0; r < 4; ++r) {
        const int row = row0 + (mf << 4) + r;
        float v = acc[mf][nf][r] + bv;
        if (EPI == 1) v = fmaxf(v, 0.f);
        if (EPI == 2) {
          Cf[(size_t)row * N + col] = v;
        } else if (EPI == 3) {
          size_t vt = ((size_t)(row >> 7) << 17) + ((size_t)(col & 127) << 10) +
                      ((row & 127) << 3) + (col >> 7);
          Cb[vt] = (__bf16)v;
        } else {
          Cb[(size_t)row * N + col] = (__bf16)v;
        }
      }
    }
  }
}

// ---------------- flash attention, QBLK=128 (8 waves), no-max exp2 softmax ---------
// g==0 blocks additionally write unnormalized bf16 P to Pun and 1/rowsum to inv0
// (selfattn = attn[0] recovered by norm_p; replaces the attn_head0 kernel).
__global__ __launch_bounds__(512, 2) void attn_flash(
    const __bf16* __restrict__ Q, const __bf16* __restrict__ K,
    const __bf16* __restrict__ VT, const __bf16* __restrict__ biasS,
    __bf16* __restrict__ ctx, __bf16* __restrict__ Pun, float* __restrict__ inv0) {
  __shared__ __bf16 Ks[64 * 128];
  __shared__ __bf16 VTs[128 * 64];
  __shared__ __bf16 Ps[8][16 * 64];

  const int bid = blockIdx.x;
  const int b = ((bid & 7) << 7) | (bid >> 3);
  const int g = b >> 3;
  const int q0 = (b & 7) << 7;
  const size_t goff = (size_t)g << 17;
  const __bf16* Qg = Q + goff;
  const __bf16* Kg = K + goff;
  const __bf16* VTg = VT + goff;

  const int t = threadIdx.x, w = t >> 6, lane = t & 63;
  const int l15 = lane & 15, lq = lane >> 4;
  const int qg = q0 + (w << 4) + l15;

  bf16x8 qf[4];
  {
    const __bf16* qrow = Qg + (size_t)qg * 128 + (lq << 3);
#pragma unroll
    for (int ec = 0; ec < 4; ++ec) qf[ec] = *(const bf16x8*)(qrow + (ec << 5));
  }
  const __bf16* bSr = biasS + ((size_t)qg << 10) + (lq << 2);

  float lrun = 0.f;
  f32x4 cacc[8] = {};

  for (int kb = 0; kb < 1024; kb += 64) {
    {
      int srow = lane >> 4;
      int sbo = (lane & 15) << 4;
#pragma unroll
      for (int i = 0; i < 2; ++i) {
        int c = (w << 1) + i;
        int r = (c << 2) + srow;
        int ke = (sbo ^ ((r & 7) << 4)) >> 1;
        load_lds16(Kg + (size_t)(kb + r) * 128 + ke, (char*)Ks + (c << 10));
      }
    }
    {
      int srow = lane >> 3;
      int sbo = (lane & 7) << 4;
#pragma unroll
      for (int i = 0; i < 2; ++i) {
        int c = (w << 1) + i;
        int e = (c << 3) + srow;
        int ke = kb + ((sbo ^ ((e & 7) << 4)) >> 1);
        load_lds16(VTg + (size_t)e * 1024 + ke, (char*)VTs + (c << 10));
      }
    }
    __syncthreads();

    f32x4 sacc[4] = {};
    __builtin_amdgcn_s_setprio(1);
#pragma unroll
    for (int ec = 0; ec < 4; ++ec) {
      const int lb = (ec << 6) + (lq << 4);
#pragma unroll
      for (int kn = 0; kn < 4; ++kn) {
        int rb = (kn << 4) + l15;
        bf16x8 kf = *(const bf16x8*)((const char*)Ks + rb * 256 + (lb ^ ((rb & 7) << 4)));
        sacc[kn] = __builtin_amdgcn_mfma_f32_16x16x32_bf16(kf, qf[ec], sacc[kn], 0, 0, 0);
      }
    }
    __builtin_amdgcn_s_setprio(0);

    const __bf16* bt = bSr + kb;
#pragma unroll
    for (int kn = 0; kn < 4; ++kn) {
      bf16x4 bb = *(const bf16x4*)(bt + (kn << 4));
      bf16x4 pk;
#pragma unroll
      for (int r = 0; r < 4; ++r) {
        float p = exp2f(fmaf(sacc[kn][r], SCALE_LOG2E, (float)bb[r]));
        lrun += p;
        pk[r] = (__bf16)p;
      }
      int bo = (kn << 5) + (lq << 3);
      *(bf16x4*)((char*)Ps[w] + l15 * 128 + (bo ^ ((l15 & 7) << 4))) = pk;
      if (g == 0)
        *(bf16x4*)(Pun + ((size_t)qg << 10) + kb + (kn << 4) + (lq << 2)) = pk;
    }
    asm volatile("s_waitcnt lgkmcnt(0)" ::: "memory");
    __builtin_amdgcn_sched_barrier(0);

    __builtin_amdgcn_s_setprio(1);
#pragma unroll
    for (int ks = 0; ks < 2; ++ks) {
      const int lb = (ks << 6) + (lq << 4);
      bf16x8 paf = *(const bf16x8*)((const char*)Ps[w] + l15 * 128 + (lb ^ ((l15 & 7) << 4)));
#pragma unroll
      for (int et = 0; et < 8; ++et) {
        int e = (et << 4) + l15;
        bf16x8 vf = *(const bf16x8*)((const char*)VTs + e * 128 + (lb ^ ((e & 7) << 4)));
        cacc[et] = __builtin_amdgcn_mfma_f32_16x16x32_bf16(paf, vf, cacc[et], 0, 0, 0);
      }
    }
    __builtin_amdgcn_s_setprio(0);
    __syncthreads();
  }

  lrun += __shfl_xor(lrun, 16);
  lrun += __shfl_xor(lrun, 32);
  float lrunR[4];
#pragma unroll
  for (int r = 0; r < 4; ++r)
    lrunR[r] = __shfl(lrun, (lane & 48) + ((lane & 48) >> 2) + r);
  __bf16* cg = ctx + goff;
  const int qr = q0 + (w << 4) + (lq << 2);
  if (g == 0 && l15 == 0) {
#pragma unroll
    for (int r = 0; r < 4; ++r) inv0[qr + r] = 1.f / lrunR[r];
  }
#pragma unroll
  for (int et = 0; et < 8; ++et)
#pragma unroll
    for (int r = 0; r < 4; ++r) {
      float v = cacc[et][r] / lrunR[r];
      cg[(size_t)(qr + r) * 128 + (et << 4) + l15] = (__bf16)v;
    }
}

// ---------------- LayerNorm(a + b) * g + beta ----------------
template <int A_BF16, int B_BF16>
__global__ __launch_bounds__(256) void ln_res(
    const void* __restrict__ aptr, const void* __restrict__ bptr,
    const float* __restrict__ gam, const float* __restrict__ bet,
    float* __restrict__ outf, __bf16* __restrict__ outb) {
  __shared__ float red[8];
  const int row = blockIdx.x, t = threadIdx.x;
  const size_t base = (size_t)row << 10;
  float a0, a1, a2, a3;
  if (A_BF16) {
    bf16x4 va = reinterpret_cast<const bf16x4*>((const __bf16*)aptr + base)[t];
    a0 = (float)va[0]; a1 = (float)va[1]; a2 = (float)va[2]; a3 = (float)va[3];
  } else {
    float4 va = reinterpret_cast<const float4*>((const float*)aptr + base)[t];
    a0 = va.x; a1 = va.y; a2 = va.z; a3 = va.w;
  }
  float b0, b1, b2, b3;
  if (B_BF16) {
    bf16x4 vb = reinterpret_cast<const bf16x4*>((const __bf16*)bptr + base)[t];
    b0 = (float)vb[0]; b1 = (float)vb[1]; b2 = (float)vb[2]; b3 = (float)vb[3];
  } else {
    float4 vb = reinterpret_cast<const float4*>((const float*)bptr + base)[t];
    b0 = vb.x; b1 = vb.y; b2 = vb.z; b3 = vb.w;
  }
  float v0 = a0 + b0, v1 = a1 + b1, v2 = a2 + b2, v3 = a3 + b3;
  float s = v0 + v1 + v2 + v3;
  float qq = v0 * v0 + v1 * v1 + v2 * v2 + v3 * v3;
#pragma unroll
  for (int d = 32; d >= 1; d >>= 1) {
    s += __shfl_xor(s, d);
    qq += __shfl_xor(qq, d);
  }
  const int w = t >> 6, lane = t & 63;
  if (lane == 0) { red[w] = s; red[4 + w] = qq; }
  __syncthreads();
  s = red[0] + red[1] + red[2] + red[3];
  qq = red[4] + red[5] + red[6] + red[7];
  const float mu = s * (1.f / 1024.f);
  const float var = qq * (1.f / 1024.f) - mu * mu;
  const float rs = rsqrtf(var + 1e-5f);
  float4 g4 = reinterpret_cast<const float4*>(gam)[t];
  float4 b4 = reinterpret_cast<const float4*>(bet)[t];
  float o0 = (v0 - mu) * rs * g4.x + b4.x;
  float o1 = (v1 - mu) * rs * g4.y + b4.y;
  float o2 = (v2 - mu) * rs * g4.z + b4.z;
  float o3 = (v3 - mu) * rs * g4.w + b4.w;
  if (outf) reinterpret_cast<float4*>(outf + base)[t] = make_float4(o0, o1, o2, o3);
  if (outb) {
    bf16x4 ob;
    ob[0] = (__bf16)o0; ob[1] = (__bf16)o1; ob[2] = (__bf16)o2; ob[3] = (__bf16)o3;
    reinterpret_cast<bf16x4*>(outb + base)[t] = ob;
  }
}

extern "C" void kernel_launch(void* const* d_in, const int* in_sizes, int n_in,
                              void* d_out, int out_size, void* d_ws, size_t ws_size,
                              hipStream_t stream) {
  (void)in_sizes; (void)n_in; (void)out_size; (void)ws_size;
  const float* x    = (const float*)d_in[0];
  const float* bias = (const float*)d_in[1];
  const float* Wq   = (const float*)d_in[2];
  const float* bq   = (const float*)d_in[3];
  const float* Wk   = (const float*)d_in[4];
  const float* bk   = (const float*)d_in[5];
  const float* Wv   = (const float*)d_in[6];
  const float* bv   = (const float*)d_in[7];
  const float* Wo   = (const float*)d_in[8];
  const float* bo   = (const float*)d_in[9];
  const float* g1   = (const float*)d_in[10];
  const float* b1l  = (const float*)d_in[11];
  const float* W1   = (const float*)d_in[12];
  const float* b1f  = (const float*)d_in[13];
  const float* W2   = (const float*)d_in[14];
  const float* b2f  = (const float*)d_in[15];
  const float* g2   = (const float*)d_in[16];
  const float* b2l  = (const float*)d_in[17];

  // ---- workspace layout (~188 MB) ----
  char* ws = (char*)d_ws;
  size_t off = 0;
  auto alloc = [&](size_t bytes) {
    char* p = ws + off;
    off += (bytes + 255) & ~(size_t)255;
    return p;
  };
  __bf16* wqb  = (__bf16*)alloc(2097152);
  __bf16* wkb  = (__bf16*)alloc(2097152);
  __bf16* wvb  = (__bf16*)alloc(2097152);
  __bf16* wob  = (__bf16*)alloc(2097152);
  __bf16* w1b  = (__bf16*)alloc(8388608);
  __bf16* w2b  = (__bf16*)alloc(8388608);
  __bf16* biasS = (__bf16*)alloc(2097152);
  __bf16* Pun  = (__bf16*)alloc(2097152);   // unnormalized P for group 0
  float*  inv0 = (float*)alloc(4096);       // per-row 1/sum for group 0
  __bf16* xb   = (__bf16*)alloc(33554432);
  __bf16* Qb   = (__bf16*)alloc(4ull * 33554432);
  __bf16* Kb   = Qb + 16777216;
  __bf16* VTb  = Kb + 16777216;
  __bf16* ctxb = VTb + 16777216;
  __bf16* hb   = Qb;                 // FFN1 out [16384,4096]; dead after attn/Wo
  __bf16* res1b = xb;                // res1 bf16 (in-place over xb)
  __bf16* attn_out_b = Qb;           // Wo out bf16
  __bf16* ffb  = ctxb;               // FFN2 out bf16 (ctxb dead after Wo)

  float* out2     = (float*)d_out;
  float* selfattn = (float*)d_out + 16777216;

  // casts
  cast_kernel<<<2048, 256, 0, stream>>>(x, xb, 16777216 / 4);
  cast_weights<<<2048, 256, 0, stream>>>(Wq, Wk, Wv, Wo, W1, W2,
                                         wqb, wkb, wvb, wob, w1b, w2b);
  scale_cast_kernel<<<512, 256, 0, stream>>>(bias, biasS, 1048576 / 4);

  // QKV projections
  gemm_bt<0><<<64 * 4, 512, 0, stream>>>(xb, wqb, bq, Qb, nullptr, 16384, 1024, 1024);
  gemm_bt<0><<<64 * 4, 512, 0, stream>>>(xb, wkb, bk, Kb, nullptr, 16384, 1024, 1024);
  gemm_bt<3><<<64 * 4, 512, 0, stream>>>(xb, wvb, bv, VTb, nullptr, 16384, 1024, 1024);

  // attention (QBLK=128; g==0 blocks emit Pun/inv0 for selfattn)
  attn_flash<<<128 * 8, 512, 0, stream>>>(Qb, Kb, VTb, biasS, ctxb, Pun, inv0);
  norm_p<<<1024, 256, 0, stream>>>(Pun, inv0, selfattn);

  // output projection -> bf16 attn_out (Qb slot)
  gemm_bt<0><<<64 * 4, 512, 0, stream>>>(ctxb, wob, bo, attn_out_b, nullptr, 16384, 1024, 1024);

  // ln1(attn_out + x[bf16]) -> res1 bf16
  ln_res<1, 1><<<16384, 256, 0, stream>>>(attn_out_b, xb, g1, b1l, nullptr, res1b);

  // FFN (r8 proven template; FFN2 writes bf16)
  gemm_bt<1><<<64 * 16, 512, 0, stream>>>(res1b, w1b, b1f, hb, nullptr, 16384, 4096, 1024);
  gemm_bt<0><<<64 * 4, 512, 0, stream>>>(hb, w2b, b2f, ffb, nullptr, 16384, 1024, 4096);

  // ln2(ff[bf16] + res1[bf16]) -> out2
  ln_res<1, 1><<<16384, 256, 0, stream>>>(ffb, res1b, g2, b2l, out2, nullptr);
}